// Round 14
// baseline (89.021 us; speedup 1.0000x reference)
//
#include <hip/hip_runtime.h>
#include <hip/hip_bf16.h>
#include <math.h>

#define BHN    64
#define SEQ    4096
#define DIM    64
#define NCHUNK 8
#define CHUNK  (SEQ / NCHUNK)        // 512 rows per pass-1 block
#define NSLOT  16                    // partial sets (2 per block)
#define KVF    (128 * DIM)           // 8192 floats of kv per head
#define STRIDE_C ((size_t)BHN * KVF + (size_t)BHN * 128)   // 532480 floats
#define KSBASE ((size_t)BHN * KVF)   // 524288
#define FRAGH  10240                 // bf16 per head: 5 t * 4 ks * 64 lanes * 8 j

typedef __bf16 bf16x8v __attribute__((ext_vector_type(8)));
typedef float  f32x4v  __attribute__((ext_vector_type(4)));

__device__ inline f32x4v mfma16(bf16x8v a, bf16x8v b, f32x4v c) {
    return __builtin_amdgcn_mfma_f32_16x16x32_bf16(a, b, c, 0, 0, 0);
}

__device__ inline unsigned pk2(float a, float b) {
    __hip_bfloat162 t(__float2bfloat16(a), __float2bfloat16(b));
    return *(unsigned*)&t;
}

// Raw workgroup barrier WITHOUT the compiler's vmcnt(0) drain (pass 2).
__device__ __forceinline__ void barrier_noflush() {
    asm volatile("s_waitcnt lgkmcnt(0)" ::: "memory");
    __builtin_amdgcn_s_barrier();
    asm volatile("" ::: "memory");
}

// ------- Pass 1 v3: direct-to-fragment gathers, no LDS/barriers in loop -------
// kv[f][m] = sum_s k_cs[s][f] * V[s][m].  Per wave: 128 rows, full 128x64 acc.
// A-frag gather K[s..s+7][dq+frow] and B-frag gather V[s..s+7][nq+frow] are
// 64B-line-coalesced dword loads straight into registers (pass-2 structure).
template<int USE_ATOMIC>
__global__ __launch_bounds__(256) void cosformer_kv_direct(
    const float* __restrict__ K, const float* __restrict__ V,
    float* __restrict__ part)
{
    __shared__ float mbuf[130][64];   // 33 KB pair-merge buffer (epilogue only)

    const int bh    = blockIdx.x / NCHUNK;
    const int chunk = blockIdx.x % NCHUNK;
    const int row0  = chunk * CHUNK;
    const float* Kb = K + (size_t)bh * SEQ * DIM;
    const float* Vb = V + (size_t)bh * SEQ * DIM;

    const int tid  = threadIdx.x;
    const int lane = tid & 63;
    const int w    = tid >> 6;        // 0..3
    const int frow = lane & 15;
    const int kgrp = lane >> 4;

    f32x4v accC[4][4], accS[4][4];
    #pragma unroll
    for (int i = 0; i < 4; ++i)
        #pragma unroll
        for (int j = 0; j < 4; ++j) {
            accC[i][j] = (f32x4v){0.f, 0.f, 0.f, 0.f};
            accS[i][j] = (f32x4v){0.f, 0.f, 0.f, 0.f};
        }
    float ksc[4] = {0.f, 0.f, 0.f, 0.f};
    float kss[4] = {0.f, 0.f, 0.f, 0.f};

    const int wrow0 = row0 + w * 128;    // wave-private 128 rows
    const float CC = 1.5707963267948966f / (float)SEQ;

    #pragma unroll 1
    for (int st = 0; st < 4; ++st) {
        const int sl = wrow0 + st * 32 + kgrp * 8;   // lane's s-base (8 rows)
        const float* kp = Kb + (size_t)sl * DIM + frow;
        const float* vp = Vb + (size_t)sl * DIM + frow;

        // issue ALL 64 gathers up front (MLP); 64B-coalesced per instruction
        float kraw[4][8], vraw[4][8];
        #pragma unroll
        for (int dq = 0; dq < 4; ++dq)
            #pragma unroll
            for (int j = 0; j < 8; ++j)
                kraw[dq][j] = kp[(size_t)j * DIM + dq * 16];
        #pragma unroll
        for (int nq = 0; nq < 4; ++nq)
            #pragma unroll
            for (int j = 0; j < 8; ++j)
                vraw[nq][j] = vp[(size_t)j * DIM + nq * 16];

        // trig overlaps load latency
        float cs_[8], sn_[8];
        #pragma unroll
        for (int j = 0; j < 8; ++j)
            __sincosf(CC * (float)(sl + j + 1), &sn_[j], &cs_[j]);

        union U { bf16x8v v; unsigned u[4]; };
        U bv[4];
        #pragma unroll
        for (int nq = 0; nq < 4; ++nq)
            #pragma unroll
            for (int i2 = 0; i2 < 4; ++i2)
                bv[nq].u[i2] = pk2(vraw[nq][2 * i2], vraw[nq][2 * i2 + 1]);

        #pragma unroll
        for (int dq = 0; dq < 4; ++dq) {
            U ac, as2;
            #pragma unroll
            for (int i2 = 0; i2 < 4; ++i2) {
                float r0 = fmaxf(kraw[dq][2 * i2],     0.f);
                float r1 = fmaxf(kraw[dq][2 * i2 + 1], 0.f);
                ac.u[i2]  = pk2(r0 * cs_[2 * i2], r1 * cs_[2 * i2 + 1]);
                as2.u[i2] = pk2(r0 * sn_[2 * i2], r1 * sn_[2 * i2 + 1]);
            }
            #pragma unroll
            for (int j = 0; j < 8; ++j) {
                float rr = fmaxf(kraw[dq][j], 0.f);
                ksc[dq] += rr * cs_[j];
                kss[dq] += rr * sn_[j];
            }
            #pragma unroll
            for (int nq = 0; nq < 4; ++nq) {
                accC[dq][nq] = mfma16(ac.v,  bv[nq].v, accC[dq][nq]);
                accS[dq][nq] = mfma16(as2.v, bv[nq].v, accS[dq][nq]);
            }
        }
    }

    // ksum: reduce over kgrp (lane bits 4,5); all lanes end with the total
    #pragma unroll
    for (int dq = 0; dq < 4; ++dq) {
        ksc[dq] += __shfl_xor(ksc[dq], 16); ksc[dq] += __shfl_xor(ksc[dq], 32);
        kss[dq] += __shfl_xor(kss[dq], 16); kss[dq] += __shfl_xor(kss[dq], 32);
    }

    if (USE_ATOMIC) {
        float* pb = part + (size_t)bh * KVF;
        float* ps = part + KSBASE + bh * 128;
        #pragma unroll
        for (int dq = 0; dq < 4; ++dq) {
            #pragma unroll
            for (int nq = 0; nq < 4; ++nq)
                #pragma unroll
                for (int r = 0; r < 4; ++r) {
                    int f = dq * 16 + kgrp * 4 + r;
                    atomicAdd(&pb[(size_t)f * DIM + nq * 16 + frow], accC[dq][nq][r]);
                    atomicAdd(&pb[(size_t)(f + 64) * DIM + nq * 16 + frow], accS[dq][nq][r]);
                }
            if (kgrp == 0) {
                atomicAdd(&ps[dq * 16 + frow], ksc[dq]);
                atomicAdd(&ps[64 + dq * 16 + frow], kss[dq]);
            }
        }
        return;
    }

    // pair-merge epilogue: (w0,w1) -> slot 2*chunk, (w2,w3) -> slot 2*chunk+1
    #pragma unroll
    for (int half = 0; half < 2; ++half) {
        if (w == 2 * half) {        // writer wave
            #pragma unroll
            for (int dq = 0; dq < 4; ++dq)
                #pragma unroll
                for (int nq = 0; nq < 4; ++nq)
                    #pragma unroll
                    for (int r = 0; r < 4; ++r) {
                        int f = dq * 16 + kgrp * 4 + r;
                        mbuf[f][nq * 16 + frow]      = accC[dq][nq][r];
                        mbuf[f + 64][nq * 16 + frow] = accS[dq][nq][r];
                    }
            if (kgrp == 0)
                #pragma unroll
                for (int dq = 0; dq < 4; ++dq) {
                    mbuf[128][dq * 16 + frow] = ksc[dq];
                    mbuf[129][dq * 16 + frow] = kss[dq];
                }
        }
        __syncthreads();
        if (w == 2 * half + 1) {    // adder wave: own + buffered -> global slot
            float* pb = part + STRIDE_C * (size_t)(chunk * 2 + half) + (size_t)bh * KVF;
            float* ps = part + STRIDE_C * (size_t)(chunk * 2 + half) + KSBASE + bh * 128;
            #pragma unroll
            for (int dq = 0; dq < 4; ++dq) {
                #pragma unroll
                for (int nq = 0; nq < 4; ++nq)
                    #pragma unroll
                    for (int r = 0; r < 4; ++r) {
                        int f = dq * 16 + kgrp * 4 + r;
                        pb[(size_t)f * DIM + nq * 16 + frow] =
                            accC[dq][nq][r] + mbuf[f][nq * 16 + frow];
                        pb[(size_t)(f + 64) * DIM + nq * 16 + frow] =
                            accS[dq][nq][r] + mbuf[f + 64][nq * 16 + frow];
                    }
                if (kgrp == 0) {
                    ps[dq * 16 + frow]      = ksc[dq] + mbuf[128][dq * 16 + frow];
                    ps[64 + dq * 16 + frow] = kss[dq] + mbuf[129][dq * 16 + frow];
                }
            }
        }
        __syncthreads();
    }
}

// ------- Reduce + pack into bf16 B-fragment layout for pass-2 MFMA -------
// bfrag[head][t][ks][lane][j]: B[k][n], k=ks*32+(lane>>4)*8+j, n=t*16+(lane&15)
// t=0..3: kv columns; t=4 col 0: ksum (denominator), other cols zero (memset).
template<int NC>
__global__ __launch_bounds__(256) void reduce_pack(
    const float* __restrict__ part, __hip_bfloat16* __restrict__ bfrag)
{
    size_t o = (size_t)blockIdx.x * 256 + threadIdx.x;
    float s = 0.f;
    #pragma unroll
    for (int c = 0; c < NC; ++c) s += part[(size_t)c * STRIDE_C + o];
    if (o < KSBASE) {
        int head = (int)(o >> 13);
        int r = (int)(o & 8191);
        int k = r >> 6, n = r & 63;
        int t = n >> 4, ks = k >> 5, lg = (k >> 3) & 3, j = k & 7;
        int lane = lg * 16 + (n & 15);
        bfrag[(size_t)head * FRAGH + (size_t)(((t * 4 + ks) * 64 + lane) * 8 + j)] =
            __float2bfloat16(s);
    } else {
        int r = (int)(o - KSBASE);
        int head = r >> 7, k = r & 127;
        int ks = k >> 5, lg = (k >> 3) & 3, j = k & 7;
        bfrag[(size_t)head * FRAGH + (size_t)(((16 + ks) * 64 + lg * 16) * 8 + j)] =
            __float2bfloat16(s);
    }
}

// ---------------- Pass 2: out = (q_cs @ kv_ext) * norm via MFMA ----------------
__global__ __launch_bounds__(256) void cosformer_out_mfma(
    const float* __restrict__ Q, const __hip_bfloat16* __restrict__ bfrag,
    float* __restrict__ out)
{
    __shared__ __hip_bfloat16 sb[FRAGH];   // 20 KB, fragment-linear
    const int head = blockIdx.x >> 3;
    const int tile = blockIdx.x & 7;
    const int tid  = threadIdx.x;

    {
        const float4* src = (const float4*)(bfrag + (size_t)head * FRAGH);
        float4* dst = (float4*)sb;
        #pragma unroll
        for (int i = 0; i < 5; ++i) dst[tid + 256 * i] = src[tid + 256 * i];
    }

    const int lane = tid & 63;
    const int w    = tid >> 6;
    const int mrow = lane & 15;
    const int kgrp = lane >> 4;

    const float* Qb = Q + (size_t)head * SEQ * DIM;
    float*       Ob = out + (size_t)head * SEQ * DIM;
    const int rowblk = tile * 512;

    float4 qb[2][4];
    #pragma unroll
    for (int m = 0; m < 2; ++m) {
        const float4* qr = (const float4*)(Qb + (size_t)(rowblk + w * 32 + m * 16 + mrow) * DIM);
        qb[m][0] = qr[kgrp * 2];
        qb[m][1] = qr[kgrp * 2 + 1];
        qb[m][2] = qr[8 + kgrp * 2];
        qb[m][3] = qr[8 + kgrp * 2 + 1];
    }

    barrier_noflush();   // sb staged; q loads stay in flight

    #pragma unroll
    for (int g = 0; g < 4; ++g) {
        const int base = rowblk + (g * 4 + w) * 32;

        bf16x8v af[2][4];
        #pragma unroll
        for (int m = 0; m < 2; ++m) {
            int arow = base + m * 16 + mrow;
            float ang = 1.5707963267948966f * (float)(arow + 1) / (float)SEQ;
            float sn, cn;
            __sincosf(ang, &sn, &cn);
            float crs = cn * 0.125f, srs = sn * 0.125f;
            float lo[8] = {qb[m][0].x, qb[m][0].y, qb[m][0].z, qb[m][0].w,
                           qb[m][1].x, qb[m][1].y, qb[m][1].z, qb[m][1].w};
            float hi[8] = {qb[m][2].x, qb[m][2].y, qb[m][2].z, qb[m][2].w,
                           qb[m][3].x, qb[m][3].y, qb[m][3].z, qb[m][3].w};
            #pragma unroll
            for (int j = 0; j < 8; ++j) {
                float rl = fmaxf(lo[j], 0.f);
                float rh = fmaxf(hi[j], 0.f);
                af[m][0][j] = (__bf16)(rl * crs);
                af[m][1][j] = (__bf16)(rh * crs);
                af[m][2][j] = (__bf16)(rl * srs);
                af[m][3][j] = (__bf16)(rh * srs);
            }
        }

        if (g < 3) {
            #pragma unroll
            for (int m = 0; m < 2; ++m) {
                const float4* qr = (const float4*)(Qb + (size_t)(rowblk + ((g + 1) * 4 + w) * 32 + m * 16 + mrow) * DIM);
                qb[m][0] = qr[kgrp * 2];
                qb[m][1] = qr[kgrp * 2 + 1];
                qb[m][2] = qr[8 + kgrp * 2];
                qb[m][3] = qr[8 + kgrp * 2 + 1];
            }
        }

        f32x4v acc[2][5];
        #pragma unroll
        for (int m = 0; m < 2; ++m)
            #pragma unroll
            for (int t = 0; t < 5; ++t)
                acc[m][t] = (f32x4v){0.f, 0.f, 0.f, 0.f};

        #pragma unroll
        for (int t = 0; t < 5; ++t)
            #pragma unroll
            for (int ks = 0; ks < 4; ++ks) {
                bf16x8v bf = *(const bf16x8v*)&sb[(size_t)(((t * 4 + ks) * 64 + lane) * 8)];
                acc[0][t] = mfma16(af[0][ks], bf, acc[0][t]);
                acc[1][t] = mfma16(af[1][ks], bf, acc[1][t]);
            }

        #pragma unroll
        for (int m = 0; m < 2; ++m) {
            #pragma unroll
            for (int r = 0; r < 4; ++r) {
                float den = __shfl(acc[m][4][r], lane & 48, 64);
                float invd = 1.0f / fmaxf(den, 1e-6f);
                int row = base + m * 16 + kgrp * 4 + r;
                float* op = Ob + (size_t)row * DIM + mrow;
                op[0]  = acc[m][0][r] * invd;
                op[16] = acc[m][1][r] * invd;
                op[32] = acc[m][2][r] * invd;
                op[48] = acc[m][3][r] * invd;
            }
        }
    }
}

extern "C" void kernel_launch(void* const* d_in, const int* in_sizes, int n_in,
                              void* d_out, int out_size, void* d_ws, size_t ws_size,
                              hipStream_t stream) {
    const float* Q = (const float*)d_in[0];
    const float* K = (const float*)d_in[1];
    const float* V = (const float*)d_in[2];
    float* out = (float*)d_out;
    float* ws  = (float*)d_ws;

    const size_t frag_bytes = (size_t)FRAGH * BHN * sizeof(__hip_bfloat16);
    const size_t need_full  = (size_t)NSLOT * STRIDE_C * sizeof(float) + frag_bytes;

    if (ws_size >= need_full) {
        float* part = ws;
        __hip_bfloat16* bfrag = (__hip_bfloat16*)(ws + (size_t)NSLOT * STRIDE_C);
        hipMemsetAsync(bfrag, 0, frag_bytes, stream);
        hipLaunchKernelGGL((cosformer_kv_direct<0>), dim3(BHN * NCHUNK), dim3(256), 0, stream,
                           K, V, part);
        hipLaunchKernelGGL((reduce_pack<NSLOT>), dim3((int)(STRIDE_C / 256)), dim3(256), 0, stream,
                           part, bfrag);
        hipLaunchKernelGGL(cosformer_out_mfma, dim3(BHN * 8), dim3(256), 0, stream,
                           Q, bfrag, out);
    } else {
        float* part = ws;
        __hip_bfloat16* bfrag = (__hip_bfloat16*)(ws + STRIDE_C);
        hipMemsetAsync(part, 0, STRIDE_C * sizeof(float), stream);
        hipMemsetAsync(bfrag, 0, frag_bytes, stream);
        hipLaunchKernelGGL((cosformer_kv_direct<1>), dim3(BHN * NCHUNK), dim3(256), 0, stream,
                           K, V, part);
        hipLaunchKernelGGL((reduce_pack<1>), dim3((int)(STRIDE_C / 256)), dim3(256), 0, stream,
                           part, bfrag);
        hipLaunchKernelGGL(cosformer_out_mfma, dim3(BHN * 8), dim3(256), 0, stream,
                           Q, bfrag, out);
    }
}